// Round 2
// baseline (261.018 us; speedup 1.0000x reference)
//
#include <hip/hip_runtime.h>
#include <math.h>

#define SEQ 2048
#define NHEAD 8
#define HDIM 64
#define BATCH 2

typedef __attribute__((ext_vector_type(8))) short short8;
typedef __attribute__((ext_vector_type(4))) float f32x4;

__device__ __forceinline__ ushort f2bf(float f) {
    union { float f; unsigned u; } v; v.f = f;
    unsigned r = v.u + 0x7FFFu + ((v.u >> 16) & 1u);   // RNE
    return (ushort)(r >> 16);
}

__device__ __forceinline__ f32x4 mfma16(short8 a, short8 b, f32x4 c) {
    return __builtin_amdgcn_mfma_f32_16x16x32_bf16(a, b, c, 0, 0, 0);
}

// global->LDS DMA, 16B per lane; ldsp must be wave-uniform (lane i lands at
// ldsp + i*16).
__device__ __forceinline__ void gld16(const void* g, void* l) {
    __builtin_amdgcn_global_load_lds(
        (const __attribute__((address_space(1))) unsigned int*)g,
        (__attribute__((address_space(3))) unsigned int*)l, 16, 0, 0);
}

// ---------------- fused prep: pack x + transpose both weights ------------
__global__ __launch_bounds__(256)
void prep(const float* __restrict__ x, const float* __restrict__ w_qkv,
          const float* __restrict__ w_out, ushort* __restrict__ xb,
          ushort* __restrict__ wqkvT, ushort* __restrict__ woutT)
{
    __shared__ ushort tile[64][66];
    const int blk = blockIdx.x, t = threadIdx.x;
    if (blk < 1024) {                       // pack x -> bf16
        const int i = (blk * 256 + t) * 8;
        float4 a = *(const float4*)&x[i];
        float4 b = *(const float4*)&x[i + 4];
        union { ushort us[8]; uint4 v; } pk;
        pk.us[0] = f2bf(a.x); pk.us[1] = f2bf(a.y); pk.us[2] = f2bf(a.z); pk.us[3] = f2bf(a.w);
        pk.us[4] = f2bf(b.x); pk.us[5] = f2bf(b.y); pk.us[6] = f2bf(b.z); pk.us[7] = f2bf(b.w);
        *(uint4*)&xb[i] = pk.v;
        return;
    }
    const float* w; ushort* wT; int K, N, n0, k0;
    if (blk < 1216) { const int s = blk - 1024; w = w_qkv; wT = wqkvT; K = 512; N = 1536; n0 = (s % 24) * 64; k0 = (s / 24) * 64; }
    else            { const int s = blk - 1216; w = w_out; wT = woutT; K = 512; N = 512;  n0 = (s % 8) * 64;  k0 = (s / 8) * 64; }
#pragma unroll
    for (int i = 0; i < 4; ++i) {
        const int slot = t + i * 256;
        const int r = slot >> 4, c4 = (slot & 15) * 4;
        float4 v = *(const float4*)&w[(size_t)(k0 + r) * N + n0 + c4];
        tile[c4 + 0][r] = f2bf(v.x);
        tile[c4 + 1][r] = f2bf(v.y);
        tile[c4 + 2][r] = f2bf(v.z);
        tile[c4 + 3][r] = f2bf(v.w);
    }
    __syncthreads();
    const int n = t >> 2, kc = (t & 3) * 16;
    union { ushort us[16]; uint4 v[2]; } o;
#pragma unroll
    for (int j = 0; j < 16; ++j) o.us[j] = tile[n][kc + j];
    *(uint4*)&wT[(size_t)(n0 + n) * K + k0 + kc]     = o.v[0];
    *(uint4*)&wT[(size_t)(n0 + n) * K + k0 + kc + 8] = o.v[1];
}

// ---------- QKV GEMM 64x128, global_load_lds staging, + RoPE epilogue ----
__global__ __launch_bounds__(256)
void gemm_qkv_rope(const ushort* __restrict__ xb, const ushort* __restrict__ wT,
                   ushort* __restrict__ qb, ushort* __restrict__ kb,
                   ushort* __restrict__ vtb)
{
    __shared__ __align__(16) ushort As[64][64];    // unpadded: DMA target
    __shared__ __align__(16) ushort Bs[128][64];
    const int t = threadIdx.x, lane = t & 63, w = t >> 6;
    const int quad = lane >> 4, l16 = lane & 15;
    const int m0 = blockIdx.y * 64, n0 = blockIdx.x * 128;
    const int mw = (w >> 1) * 32, nw = (w & 1) * 64;
    const int krow = lane >> 3, kcol = (lane & 7) * 8;   // DMA lane mapping
    f32x4 acc[2][4] = {};

    for (int k0 = 0; k0 < 512; k0 += 64) {
        __syncthreads();   // previous tile's readers done
        gld16(&xb[(size_t)(m0 + w * 8 + krow) * 512 + k0 + kcol],        &As[w * 8][0]);
        gld16(&xb[(size_t)(m0 + (w + 4) * 8 + krow) * 512 + k0 + kcol],  &As[(w + 4) * 8][0]);
#pragma unroll
        for (int jj = 0; jj < 4; ++jj) {
            const int j = w * 4 + jj;
            gld16(&wT[(size_t)(n0 + j * 8 + krow) * 512 + k0 + kcol], &Bs[j * 8][0]);
        }
        __syncthreads();   // vmcnt drained -> tiles ready
#pragma unroll
        for (int ks = 0; ks < 2; ++ks) {
            short8 a[2], b[4];
#pragma unroll
            for (int i = 0; i < 2; ++i)
                a[i] = *(const short8*)&As[mw + i * 16 + l16][ks * 32 + quad * 8];
#pragma unroll
            for (int j = 0; j < 4; ++j)
                b[j] = *(const short8*)&Bs[nw + j * 16 + l16][ks * 32 + quad * 8];
#pragma unroll
            for (int i = 0; i < 2; ++i)
#pragma unroll
                for (int j = 0; j < 4; ++j)
                    acc[i][j] = mfma16(a[i], b[j], acc[i][j]);
        }
    }

    const int sec = (n0 + nw) >> 9;   // 0=q 1=k 2=v, wave-uniform
    if (sec == 2) {
#pragma unroll
        for (int i = 0; i < 2; ++i) {
            const int m = m0 + mw + i * 16 + quad * 4;
            const int bidx = m >> 11, n = m & 2047;
#pragma unroll
            for (int j = 0; j < 4; ++j) {
                const int nc = n0 + nw + j * 16 + l16;
                const int d = nc & 63, h = (nc >> 6) & 7;
                ushort4 pk;
                pk.x = f2bf(acc[i][j][0]); pk.y = f2bf(acc[i][j][1]);
                pk.z = f2bf(acc[i][j][2]); pk.w = f2bf(acc[i][j][3]);
                *(ushort4*)&vtb[(((size_t)bidx * 8 + h) * 64 + d) * 2048 + n] = pk;
            }
        }
    } else {
        ushort* dst = (sec == 0) ? qb : kb;
        const float scale = (sec == 0) ? 0.125f : 1.0f;
#pragma unroll
        for (int j = 0; j < 4; ++j) {
            const int nc = n0 + nw + j * 16 + l16;
            const int d = nc & 63, h = (nc >> 6) & 7;
            const float inv = __expf(-(float)(d & ~1) * (9.2103403719761836f / 64.0f));
#pragma unroll
            for (int i = 0; i < 2; ++i)
#pragma unroll
            for (int r = 0; r < 4; ++r) {
                const int m = m0 + mw + i * 16 + quad * 4 + r;
                const int bidx = m >> 11, n = m & 2047;
                float sn, cs;
                __sincosf((float)n * inv, &sn, &cs);
                const float vacc = acc[i][j][r];
                const float partner = __shfl_xor(vacc, 1);
                const float rot = (d & 1) ? (vacc * cs + partner * sn)
                                          : (vacc * cs - partner * sn);
                dst[(((size_t)bidx * 8 + h) * 2048 + n) * 64 + d] = f2bf(rot * scale);
            }
        }
    }
}

// ---------- flash attention: QBLK=128, counted-vmcnt pipeline ------------
// R2 changes:
//  (1) QBLK 64->128 (512 threads, 8 waves, grid 16x8x2=256 blocks): K/V
//      requested bytes halve (16 readers per (b,h) instead of 32). Per-wave
//      compute identical (wave owns 16 q-rows). LDS 114KB -> 1 block/CU,
//      8 waves/CU (same resident waves as before).
//  (2) T4 counted-vmcnt pipeline: raw s_barrier + "s_waitcnt vmcnt(6)" --
//      never drain to 0 in the loop. Tile t+1's 6 DMA loads stay in flight
//      across all of compute(t); __syncthreads' structural vmcnt(0) drain
//      (which nullified R1's prefetch) is gone. vmcnt counting is safe by
//      in-order retirement: tile t's 6 ops are the oldest when we wait.
__global__ __launch_bounds__(512)
void flash_attn_mfma(const ushort* __restrict__ qb, const ushort* __restrict__ kb,
                     const ushort* __restrict__ vtb, const float* __restrict__ bias,
                     ushort* __restrict__ ob)
{
    __shared__ __align__(16) ushort Ks[2][64][64];    // 16KB, swizzled, DMA tgt
    __shared__ __align__(16) ushort Vt[2][64][64];    // 16KB, [dim][seq], swz
    __shared__ __align__(16) float  Bl[2][128][64];   // 64KB bias fp32
    __shared__ __align__(16) ushort Ps[8][16][72];    // 18KB
    const int t = threadIdx.x, lane = t & 63, w = t >> 6;   // w in [0,8)
    const int quad = lane >> 4, l16 = lane & 15;
    const int q0 = blockIdx.x * 128, h = blockIdx.y, b = blockIdx.z;
    const size_t bh = (size_t)(b * NHEAD + h);
    const ushort* Q  = qb  + bh * SEQ * HDIM;
    const ushort* Kp = kb  + bh * SEQ * HDIM;
    const ushort* VT = vtb + bh * HDIM * SEQ;

    short8 qf[2];
    qf[0] = *(const short8*)&Q[(size_t)(q0 + w * 16 + l16) * HDIM + quad * 8];
    qf[1] = *(const short8*)&Q[(size_t)(q0 + w * 16 + l16) * HDIM + 32 + quad * 8];

    f32x4 oacc[4] = {};
    float lsum[4] = {};
    const int krow = lane >> 3;                       // K/V DMA row-in-8
    const int kcolsw = ((lane & 7) ^ krow) * 8;       // swizzled source chunk
    const int brow = lane >> 4, bcol = (lane & 15) * 4;  // bias DMA mapping

    // swizzled read columns: logical chunk (ks*4+quad) at row with row&7==l16&7
    const int sw = l16 & 7;
    const int c0 = (quad ^ sw) * 8;           // ks=0
    const int c1 = ((quad + 4) ^ sw) * 8;     // ks=1

    // one stage = 6 gld16 per thread (512 thr): K 8KB, V 8KB, bias 32KB
    auto stage = [&](int buf, int it_) {
        const int k0 = it_ * 64;
        gld16(&Kp[(size_t)(k0 + w * 8 + krow) * HDIM + kcolsw], &Ks[buf][w * 8][0]);
        gld16(&VT[(size_t)(w * 8 + krow) * SEQ + k0 + kcolsw],  &Vt[buf][w * 8][0]);
#pragma unroll
        for (int j = 0; j < 4; ++j)
            gld16(&bias[((size_t)h * SEQ + q0 + j * 32 + w * 4 + brow) * SEQ + k0 + bcol],
                  &Bl[buf][j * 32 + w * 4][0]);
    };

    stage(0, 0);                         // tile 0 in flight

    for (int it = 0; it < 32; ++it) {
        const int cur = it & 1;
        __builtin_amdgcn_s_barrier();    // A: all readers of buf cur^1 done
        if (it + 1 < 32) {
            stage(cur ^ 1, it + 1);      // 6 loads for t+1 -> stay in flight
            asm volatile("s_waitcnt vmcnt(6)" ::: "memory");   // tile it landed
        } else {
            asm volatile("s_waitcnt vmcnt(0)" ::: "memory");
        }
        __builtin_amdgcn_s_barrier();    // B: tile it resident for all waves
        __builtin_amdgcn_sched_barrier(0);

        // S = Q K^T  (swizzled K reads)
        f32x4 sacc[4] = {};
#pragma unroll
        for (int s = 0; s < 4; ++s) {
            short8 kf0 = *(const short8*)&Ks[cur][s * 16 + l16][c0];
            sacc[s] = mfma16(qf[0], kf0, sacc[s]);
            short8 kf1 = *(const short8*)&Ks[cur][s * 16 + l16][c1];
            sacc[s] = mfma16(qf[1], kf1, sacc[s]);
        }

        // p = exp(s + bias); row-sum deferred to epilogue
#pragma unroll
        for (int r = 0; r < 4; ++r)
#pragma unroll
            for (int s = 0; s < 4; ++s) {
                const float p = __expf(sacc[s][r] + Bl[cur][w * 16 + quad * 4 + r][s * 16 + l16]);
                lsum[r] += p;
                Ps[w][quad * 4 + r][s * 16 + l16] = f2bf(p);
            }
        asm volatile("" ::: "memory");   // per-wave Ps: order writes before reads

        // O += P V  (swizzled V reads)
#pragma unroll
        for (int ks = 0; ks < 2; ++ks) {
            short8 pf = *(const short8*)&Ps[w][l16][ks * 32 + quad * 8];
            const int cc = ks ? c1 : c0;
#pragma unroll
            for (int s = 0; s < 4; ++s) {
                short8 vf = *(const short8*)&Vt[cur][s * 16 + l16][cc];
                oacc[s] = mfma16(pf, vf, oacc[s]);
            }
        }
    }

    // epilogue: cross-lane row-sum, normalize, write attnb [4096][512]
#pragma unroll
    for (int r = 0; r < 4; ++r) {
        float rs = lsum[r];
        rs += __shfl_xor(rs, 1, 16);
        rs += __shfl_xor(rs, 2, 16);
        rs += __shfl_xor(rs, 4, 16);
        rs += __shfl_xor(rs, 8, 16);
        const float invl = 1.0f / rs;
        const size_t m = (size_t)b * SEQ + q0 + w * 16 + quad * 4 + r;
#pragma unroll
        for (int s = 0; s < 4; ++s)
            ob[m * 512 + h * HDIM + s * 16 + l16] = f2bf(oacc[s][r] * invl);
    }
}

// ---------- out GEMM 64x64, global_load_lds staging ----------------------
__global__ __launch_bounds__(256)
void gemm_out(const ushort* __restrict__ Ab, const ushort* __restrict__ wT,
              float* __restrict__ C)
{
    __shared__ __align__(16) ushort As[64][64];
    __shared__ __align__(16) ushort Bs[64][64];
    const int t = threadIdx.x, lane = t & 63, w = t >> 6;
    const int quad = lane >> 4, l16 = lane & 15;
    const int m0 = blockIdx.y * 64, n0 = blockIdx.x * 64;
    const int mw = (w >> 1) * 32, nw = (w & 1) * 32;
    const int krow = lane >> 3, kcol = (lane & 7) * 8;
    f32x4 acc[2][2] = {};

    for (int k0 = 0; k0 < 512; k0 += 64) {
        __syncthreads();
        gld16(&Ab[(size_t)(m0 + w * 8 + krow) * 512 + k0 + kcol],       &As[w * 8][0]);
        gld16(&Ab[(size_t)(m0 + (w + 4) * 8 + krow) * 512 + k0 + kcol], &As[(w + 4) * 8][0]);
        gld16(&wT[(size_t)(n0 + w * 8 + krow) * 512 + k0 + kcol],       &Bs[w * 8][0]);
        gld16(&wT[(size_t)(n0 + (w + 4) * 8 + krow) * 512 + k0 + kcol], &Bs[(w + 4) * 8][0]);
        __syncthreads();
#pragma unroll
        for (int ks = 0; ks < 2; ++ks) {
            short8 a[2], b[2];
#pragma unroll
            for (int i = 0; i < 2; ++i)
                a[i] = *(const short8*)&As[mw + i * 16 + l16][ks * 32 + quad * 8];
#pragma unroll
            for (int j = 0; j < 2; ++j)
                b[j] = *(const short8*)&Bs[nw + j * 16 + l16][ks * 32 + quad * 8];
#pragma unroll
            for (int i = 0; i < 2; ++i)
#pragma unroll
                for (int j = 0; j < 2; ++j)
                    acc[i][j] = mfma16(a[i], b[j], acc[i][j]);
        }
    }
#pragma unroll
    for (int i = 0; i < 2; ++i)
#pragma unroll
    for (int r = 0; r < 4; ++r) {
        const int m = m0 + mw + i * 16 + quad * 4 + r;
#pragma unroll
        for (int j = 0; j < 2; ++j)
            C[(size_t)m * 512 + n0 + nw + j * 16 + l16] = acc[i][j][r];
    }
}

extern "C" void kernel_launch(void* const* d_in, const int* in_sizes, int n_in,
                              void* d_out, int out_size, void* d_ws, size_t ws_size,
                              hipStream_t stream)
{
    const float* x        = (const float*)d_in[0];
    const float* pos_bias = (const float*)d_in[1];
    const float* w_qkv    = (const float*)d_in[2];
    const float* w_out    = (const float*)d_in[3];
    float* out = (float*)d_out;

    char* ws = (char*)d_ws;
    ushort* xb     = (ushort*)(ws);                            // 4 MB
    ushort* wqkvT  = (ushort*)(ws + 4194304);                  // 1.5 MB
    ushort* woutT  = (ushort*)(ws + 5767168);                  // 0.5 MB
    ushort* qb     = (ushort*)(ws + 6291456);                  // 4 MB
    ushort* kb     = (ushort*)(ws + 10485760);                 // 4 MB
    ushort* vtb    = (ushort*)(ws + 14680064);                 // 4 MB (V^T)
    ushort* attnb  = (ushort*)(ws + 18874368);                 // 4 MB

    prep<<<1280, 256, 0, stream>>>(x, w_qkv, w_out, xb, wqkvT, woutT);
    gemm_qkv_rope<<<dim3(12, 64), 256, 0, stream>>>(xb, wqkvT, qb, kb, vtb);
    flash_attn_mfma<<<dim3(SEQ / 128, NHEAD, BATCH), 512, 0, stream>>>(qb, kb, vtb, pos_bias, attnb);
    gemm_out<<<dim3(8, 64), 256, 0, stream>>>(attnb, woutT, out);
}

// Round 3
// 251.095 us; speedup vs baseline: 1.0395x; 1.0395x over previous
//
#include <hip/hip_runtime.h>
#include <math.h>

#define SEQ 2048
#define NHEAD 8
#define HDIM 64
#define BATCH 2

typedef __attribute__((ext_vector_type(8))) short short8;
typedef __attribute__((ext_vector_type(4))) float f32x4;

__device__ __forceinline__ ushort f2bf(float f) {
    union { float f; unsigned u; } v; v.f = f;
    unsigned r = v.u + 0x7FFFu + ((v.u >> 16) & 1u);   // RNE
    return (ushort)(r >> 16);
}

__device__ __forceinline__ f32x4 mfma16(short8 a, short8 b, f32x4 c) {
    return __builtin_amdgcn_mfma_f32_16x16x32_bf16(a, b, c, 0, 0, 0);
}

// global->LDS DMA, 16B per lane; ldsp must be wave-uniform (lane i lands at
// ldsp + i*16).
__device__ __forceinline__ void gld16(const void* g, void* l) {
    __builtin_amdgcn_global_load_lds(
        (const __attribute__((address_space(1))) unsigned int*)g,
        (__attribute__((address_space(3))) unsigned int*)l, 16, 0, 0);
}

// ---------------- fused prep: pack x + transpose both weights ------------
__global__ __launch_bounds__(256)
void prep(const float* __restrict__ x, const float* __restrict__ w_qkv,
          const float* __restrict__ w_out, ushort* __restrict__ xb,
          ushort* __restrict__ wqkvT, ushort* __restrict__ woutT)
{
    __shared__ ushort tile[64][66];
    const int blk = blockIdx.x, t = threadIdx.x;
    if (blk < 1024) {                       // pack x -> bf16
        const int i = (blk * 256 + t) * 8;
        float4 a = *(const float4*)&x[i];
        float4 b = *(const float4*)&x[i + 4];
        union { ushort us[8]; uint4 v; } pk;
        pk.us[0] = f2bf(a.x); pk.us[1] = f2bf(a.y); pk.us[2] = f2bf(a.z); pk.us[3] = f2bf(a.w);
        pk.us[4] = f2bf(b.x); pk.us[5] = f2bf(b.y); pk.us[6] = f2bf(b.z); pk.us[7] = f2bf(b.w);
        *(uint4*)&xb[i] = pk.v;
        return;
    }
    const float* w; ushort* wT; int K, N, n0, k0;
    if (blk < 1216) { const int s = blk - 1024; w = w_qkv; wT = wqkvT; K = 512; N = 1536; n0 = (s % 24) * 64; k0 = (s / 24) * 64; }
    else            { const int s = blk - 1216; w = w_out; wT = woutT; K = 512; N = 512;  n0 = (s % 8) * 64;  k0 = (s / 8) * 64; }
#pragma unroll
    for (int i = 0; i < 4; ++i) {
        const int slot = t + i * 256;
        const int r = slot >> 4, c4 = (slot & 15) * 4;
        float4 v = *(const float4*)&w[(size_t)(k0 + r) * N + n0 + c4];
        tile[c4 + 0][r] = f2bf(v.x);
        tile[c4 + 1][r] = f2bf(v.y);
        tile[c4 + 2][r] = f2bf(v.z);
        tile[c4 + 3][r] = f2bf(v.w);
    }
    __syncthreads();
    const int n = t >> 2, kc = (t & 3) * 16;
    union { ushort us[16]; uint4 v[2]; } o;
#pragma unroll
    for (int j = 0; j < 16; ++j) o.us[j] = tile[n][kc + j];
    *(uint4*)&wT[(size_t)(n0 + n) * K + k0 + kc]     = o.v[0];
    *(uint4*)&wT[(size_t)(n0 + n) * K + k0 + kc + 8] = o.v[1];
}

// ---------- QKV GEMM 64x128, global_load_lds staging, + RoPE epilogue ----
__global__ __launch_bounds__(256)
void gemm_qkv_rope(const ushort* __restrict__ xb, const ushort* __restrict__ wT,
                   ushort* __restrict__ qb, ushort* __restrict__ kb,
                   ushort* __restrict__ vtb)
{
    __shared__ __align__(16) ushort As[64][64];    // unpadded: DMA target
    __shared__ __align__(16) ushort Bs[128][64];
    const int t = threadIdx.x, lane = t & 63, w = t >> 6;
    const int quad = lane >> 4, l16 = lane & 15;
    const int m0 = blockIdx.y * 64, n0 = blockIdx.x * 128;
    const int mw = (w >> 1) * 32, nw = (w & 1) * 64;
    const int krow = lane >> 3, kcol = (lane & 7) * 8;   // DMA lane mapping
    f32x4 acc[2][4] = {};

    for (int k0 = 0; k0 < 512; k0 += 64) {
        __syncthreads();   // previous tile's readers done
        gld16(&xb[(size_t)(m0 + w * 8 + krow) * 512 + k0 + kcol],        &As[w * 8][0]);
        gld16(&xb[(size_t)(m0 + (w + 4) * 8 + krow) * 512 + k0 + kcol],  &As[(w + 4) * 8][0]);
#pragma unroll
        for (int jj = 0; jj < 4; ++jj) {
            const int j = w * 4 + jj;
            gld16(&wT[(size_t)(n0 + j * 8 + krow) * 512 + k0 + kcol], &Bs[j * 8][0]);
        }
        __syncthreads();   // vmcnt drained -> tiles ready
#pragma unroll
        for (int ks = 0; ks < 2; ++ks) {
            short8 a[2], b[4];
#pragma unroll
            for (int i = 0; i < 2; ++i)
                a[i] = *(const short8*)&As[mw + i * 16 + l16][ks * 32 + quad * 8];
#pragma unroll
            for (int j = 0; j < 4; ++j)
                b[j] = *(const short8*)&Bs[nw + j * 16 + l16][ks * 32 + quad * 8];
#pragma unroll
            for (int i = 0; i < 2; ++i)
#pragma unroll
                for (int j = 0; j < 4; ++j)
                    acc[i][j] = mfma16(a[i], b[j], acc[i][j]);
        }
    }

    const int sec = (n0 + nw) >> 9;   // 0=q 1=k 2=v, wave-uniform
    if (sec == 2) {
#pragma unroll
        for (int i = 0; i < 2; ++i) {
            const int m = m0 + mw + i * 16 + quad * 4;
            const int bidx = m >> 11, n = m & 2047;
#pragma unroll
            for (int j = 0; j < 4; ++j) {
                const int nc = n0 + nw + j * 16 + l16;
                const int d = nc & 63, h = (nc >> 6) & 7;
                ushort4 pk;
                pk.x = f2bf(acc[i][j][0]); pk.y = f2bf(acc[i][j][1]);
                pk.z = f2bf(acc[i][j][2]); pk.w = f2bf(acc[i][j][3]);
                *(ushort4*)&vtb[(((size_t)bidx * 8 + h) * 64 + d) * 2048 + n] = pk;
            }
        }
    } else {
        ushort* dst = (sec == 0) ? qb : kb;
        const float scale = (sec == 0) ? 0.125f : 1.0f;
#pragma unroll
        for (int j = 0; j < 4; ++j) {
            const int nc = n0 + nw + j * 16 + l16;
            const int d = nc & 63, h = (nc >> 6) & 7;
            const float inv = __expf(-(float)(d & ~1) * (9.2103403719761836f / 64.0f));
#pragma unroll
            for (int i = 0; i < 2; ++i)
#pragma unroll
            for (int r = 0; r < 4; ++r) {
                const int m = m0 + mw + i * 16 + quad * 4 + r;
                const int bidx = m >> 11, n = m & 2047;
                float sn, cs;
                __sincosf((float)n * inv, &sn, &cs);
                const float vacc = acc[i][j][r];
                const float partner = __shfl_xor(vacc, 1);
                const float rot = (d & 1) ? (vacc * cs + partner * sn)
                                          : (vacc * cs - partner * sn);
                dst[(((size_t)bidx * 8 + h) * 2048 + n) * 64 + d] = f2bf(rot * scale);
            }
        }
    }
}

// ---------- flash attention R3: reg-bias + depth-2 K/V, 1 barrier/iter ---
// - bias: per-thread registers (each element used by exactly ONE lane; LDS
//   staging was pure overhead + coupled bias latency to the barrier).
//   Issued 2 iterations ahead; waited by compiler's per-wave vmcnt before
//   softmax, NOT by the barrier.
// - K/V: triple-buffered LDS via gld16, issued 2 iterations ahead. Top-of-
//   loop "s_waitcnt vmcnt(36)" drains ONLY tile it's 4 K/V DMAs (16 bias +
//   next 20 stay in flight; per-iter issue group = stage[4] then bias[16],
//   order pinned by asm memory barriers).
// - ONE s_barrier/iter: buffer written at iter it is (it+2)%3, last read at
//   iter it-1 (before this barrier); wave skew < 1 iter => safe.
__global__ __launch_bounds__(256)
void flash_attn_mfma(const ushort* __restrict__ qb, const ushort* __restrict__ kb,
                     const ushort* __restrict__ vtb, const float* __restrict__ bias,
                     ushort* __restrict__ ob)
{
    __shared__ __align__(16) ushort Ks[3][64][64];   // 24KB, swizzled, DMA tgt
    __shared__ __align__(16) ushort Vt[3][64][64];   // 24KB, [dim][seq], swz
    __shared__ __align__(16) ushort Ps[4][16][72];   // 9KB
    const int t = threadIdx.x, lane = t & 63, w = t >> 6;   // w in [0,4)
    const int quad = lane >> 4, l16 = lane & 15;
    const int q0 = blockIdx.x * 64, h = blockIdx.y, b = blockIdx.z;
    const size_t bh = (size_t)(b * NHEAD + h);
    const ushort* Q  = qb  + bh * SEQ * HDIM;
    const ushort* Kp = kb  + bh * SEQ * HDIM;
    const ushort* VT = vtb + bh * HDIM * SEQ;
    const float*  Bp = bias + ((size_t)h * SEQ + q0 + w * 16) * SEQ;  // wave's rows

    f32x4 oacc[4] = {};
    float lsum[4] = {};
    const int krow = lane >> 3;                       // K/V DMA row-in-8
    const int kcolsw = ((lane & 7) ^ krow) * 8;       // swizzled source chunk

    // swizzled read columns: logical chunk (ks*4+quad) at row with row&7==l16&7
    const int sw = l16 & 7;
    const int c0 = (quad ^ sw) * 8;           // ks=0
    const int c1 = ((quad + 4) ^ sw) * 8;     // ks=1

    short8 qf[2];
    qf[0] = *(const short8*)&Q[(size_t)(q0 + w * 16 + l16) * HDIM + quad * 8];
    qf[1] = *(const short8*)&Q[(size_t)(q0 + w * 16 + l16) * HDIM + 32 + quad * 8];
    asm volatile("" ::: "memory");   // Q loads issued before staging groups

    float b0[16], b1[16];

    // stage K/V tile IT_ into LDS buffer BUF (4 gld16 / thread, 4 waves)
#define FA_STAGE(BUF, IT_)                                                          \
    {                                                                               \
        const int k2_ = (IT_) * 64;                                                 \
        gld16(&Kp[(size_t)(k2_ + w * 8 + krow) * HDIM + kcolsw],       &Ks[BUF][w * 8][0]);       \
        gld16(&Kp[(size_t)(k2_ + (w + 4) * 8 + krow) * HDIM + kcolsw], &Ks[BUF][(w + 4) * 8][0]); \
        gld16(&VT[(size_t)(w * 8 + krow) * SEQ + k2_ + kcolsw],        &Vt[BUF][w * 8][0]);       \
        gld16(&VT[(size_t)((w + 4) * 8 + krow) * SEQ + k2_ + kcolsw],  &Vt[BUF][(w + 4) * 8][0]); \
    }

    // bias tile IT_ -> 16 fp32 registers (row quad*4+r, col s*16+l16)
#define FA_BIAS(BREG, IT_)                                                          \
    {                                                                               \
        const int k2_ = (IT_) * 64;                                                 \
        _Pragma("unroll")                                                           \
        for (int r = 0; r < 4; ++r)                                                 \
            _Pragma("unroll")                                                       \
            for (int s = 0; s < 4; ++s)                                             \
                BREG[r * 4 + s] = Bp[(size_t)(quad * 4 + r) * SEQ + k2_ + s * 16 + l16]; \
    }

    // one iteration. WCNT: vmcnt immediate at top. REFILL: issue it+2 loads.
#define FA_BODY(IT, BCUR, REFILL, WCNT)                                             \
    {                                                                               \
        asm volatile("s_waitcnt vmcnt(" #WCNT ")" ::: "memory");                    \
        __builtin_amdgcn_s_barrier();                                               \
        const int cb_ = (IT) % 3;                                                   \
        if (REFILL) {                                                               \
            FA_STAGE(((IT) + 2) % 3, (IT) + 2);                                     \
            asm volatile("" ::: "memory");   /* pin: stage before bias */           \
        }                                                                           \
        f32x4 sacc[4] = {};                                                         \
        __builtin_amdgcn_s_setprio(1);                                              \
        _Pragma("unroll")                                                           \
        for (int s = 0; s < 4; ++s) {                                               \
            short8 kf0 = *(const short8*)&Ks[cb_][s * 16 + l16][c0];                \
            sacc[s] = mfma16(qf[0], kf0, sacc[s]);                                  \
            short8 kf1 = *(const short8*)&Ks[cb_][s * 16 + l16][c1];                \
            sacc[s] = mfma16(qf[1], kf1, sacc[s]);                                  \
        }                                                                           \
        __builtin_amdgcn_s_setprio(0);                                              \
        _Pragma("unroll")                                                           \
        for (int r = 0; r < 4; ++r)                                                 \
            _Pragma("unroll")                                                       \
            for (int s = 0; s < 4; ++s) {                                           \
                const float p = __expf(sacc[s][r] + BCUR[r * 4 + s]);               \
                lsum[r] += p;                                                       \
                Ps[w][quad * 4 + r][s * 16 + l16] = f2bf(p);                        \
            }                                                                       \
        if (REFILL) FA_BIAS(BCUR, (IT) + 2);                                        \
        asm volatile("" ::: "memory");   /* Ps writes before Ps reads */            \
        __builtin_amdgcn_s_setprio(1);                                              \
        _Pragma("unroll")                                                           \
        for (int ks = 0; ks < 2; ++ks) {                                            \
            short8 pf = *(const short8*)&Ps[w][l16][ks * 32 + quad * 8];            \
            const int cc_ = ks ? c1 : c0;                                           \
            _Pragma("unroll")                                                       \
            for (int s = 0; s < 4; ++s) {                                           \
                short8 vf = *(const short8*)&Vt[cb_][s * 16 + l16][cc_];            \
                oacc[s] = mfma16(pf, vf, oacc[s]);                                  \
            }                                                                       \
        }                                                                           \
        __builtin_amdgcn_s_setprio(0);                                              \
    }

    // prologue: group(0) then group(1), order pinned
    FA_STAGE(0, 0);
    asm volatile("" ::: "memory");
    FA_BIAS(b0, 0);
    asm volatile("" ::: "memory");
    FA_STAGE(1, 1);
    asm volatile("" ::: "memory");
    FA_BIAS(b1, 1);

    for (int i2 = 0; i2 < 15; ++i2) {
        FA_BODY(2 * i2,     b0, 1, 36);
        FA_BODY(2 * i2 + 1, b1, 1, 36);
    }
    FA_BODY(30, b0, 0, 36);
    FA_BODY(31, b1, 0, 16);

#undef FA_BODY
#undef FA_BIAS
#undef FA_STAGE

    // epilogue: cross-lane row-sum, normalize, write attnb [4096][512]
#pragma unroll
    for (int r = 0; r < 4; ++r) {
        float rs = lsum[r];
        rs += __shfl_xor(rs, 1, 16);
        rs += __shfl_xor(rs, 2, 16);
        rs += __shfl_xor(rs, 4, 16);
        rs += __shfl_xor(rs, 8, 16);
        const float invl = 1.0f / rs;
        const size_t m = (size_t)b * SEQ + q0 + w * 16 + quad * 4 + r;
#pragma unroll
        for (int s = 0; s < 4; ++s)
            ob[m * 512 + h * HDIM + s * 16 + l16] = f2bf(oacc[s][r] * invl);
    }
}

// ---------- out GEMM 64x64, global_load_lds staging ----------------------
__global__ __launch_bounds__(256)
void gemm_out(const ushort* __restrict__ Ab, const ushort* __restrict__ wT,
              float* __restrict__ C)
{
    __shared__ __align__(16) ushort As[64][64];
    __shared__ __align__(16) ushort Bs[64][64];
    const int t = threadIdx.x, lane = t & 63, w = t >> 6;
    const int quad = lane >> 4, l16 = lane & 15;
    const int m0 = blockIdx.y * 64, n0 = blockIdx.x * 64;
    const int mw = (w >> 1) * 32, nw = (w & 1) * 32;
    const int krow = lane >> 3, kcol = (lane & 7) * 8;
    f32x4 acc[2][2] = {};

    for (int k0 = 0; k0 < 512; k0 += 64) {
        __syncthreads();
        gld16(&Ab[(size_t)(m0 + w * 8 + krow) * 512 + k0 + kcol],       &As[w * 8][0]);
        gld16(&Ab[(size_t)(m0 + (w + 4) * 8 + krow) * 512 + k0 + kcol], &As[(w + 4) * 8][0]);
        gld16(&wT[(size_t)(n0 + w * 8 + krow) * 512 + k0 + kcol],       &Bs[w * 8][0]);
        gld16(&wT[(size_t)(n0 + (w + 4) * 8 + krow) * 512 + k0 + kcol], &Bs[(w + 4) * 8][0]);
        __syncthreads();
#pragma unroll
        for (int ks = 0; ks < 2; ++ks) {
            short8 a[2], b[2];
#pragma unroll
            for (int i = 0; i < 2; ++i)
                a[i] = *(const short8*)&As[mw + i * 16 + l16][ks * 32 + quad * 8];
#pragma unroll
            for (int j = 0; j < 2; ++j)
                b[j] = *(const short8*)&Bs[nw + j * 16 + l16][ks * 32 + quad * 8];
#pragma unroll
            for (int i = 0; i < 2; ++i)
#pragma unroll
                for (int j = 0; j < 2; ++j)
                    acc[i][j] = mfma16(a[i], b[j], acc[i][j]);
        }
    }
#pragma unroll
    for (int i = 0; i < 2; ++i)
#pragma unroll
    for (int r = 0; r < 4; ++r) {
        const int m = m0 + mw + i * 16 + quad * 4 + r;
#pragma unroll
        for (int j = 0; j < 2; ++j)
            C[(size_t)m * 512 + n0 + nw + j * 16 + l16] = acc[i][j][r];
    }
}

extern "C" void kernel_launch(void* const* d_in, const int* in_sizes, int n_in,
                              void* d_out, int out_size, void* d_ws, size_t ws_size,
                              hipStream_t stream)
{
    const float* x        = (const float*)d_in[0];
    const float* pos_bias = (const float*)d_in[1];
    const float* w_qkv    = (const float*)d_in[2];
    const float* w_out    = (const float*)d_in[3];
    float* out = (float*)d_out;

    char* ws = (char*)d_ws;
    ushort* xb     = (ushort*)(ws);                            // 4 MB
    ushort* wqkvT  = (ushort*)(ws + 4194304);                  // 1.5 MB
    ushort* woutT  = (ushort*)(ws + 5767168);                  // 0.5 MB
    ushort* qb     = (ushort*)(ws + 6291456);                  // 4 MB
    ushort* kb     = (ushort*)(ws + 10485760);                 // 4 MB
    ushort* vtb    = (ushort*)(ws + 14680064);                 // 4 MB (V^T)
    ushort* attnb  = (ushort*)(ws + 18874368);                 // 4 MB

    prep<<<1280, 256, 0, stream>>>(x, w_qkv, w_out, xb, wqkvT, woutT);
    gemm_qkv_rope<<<dim3(12, 64), 256, 0, stream>>>(xb, wqkvT, qb, kb, vtb);
    flash_attn_mfma<<<dim3(SEQ / 64, NHEAD, BATCH), 256, 0, stream>>>(qb, kb, vtb, pos_bias, attnb);
    gemm_out<<<dim3(8, 64), 256, 0, stream>>>(attnb, woutT, out);
}

// Round 4
// 251.021 us; speedup vs baseline: 1.0398x; 1.0003x over previous
//
#include <hip/hip_runtime.h>
#include <math.h>

#define SEQ 2048
#define NHEAD 8
#define HDIM 64
#define BATCH 2

typedef __attribute__((ext_vector_type(8))) short short8;
typedef __attribute__((ext_vector_type(4))) float f32x4;

__device__ __forceinline__ ushort f2bf(float f) {
    union { float f; unsigned u; } v; v.f = f;
    unsigned r = v.u + 0x7FFFu + ((v.u >> 16) & 1u);   // RNE
    return (ushort)(r >> 16);
}

__device__ __forceinline__ f32x4 mfma16(short8 a, short8 b, f32x4 c) {
    return __builtin_amdgcn_mfma_f32_16x16x32_bf16(a, b, c, 0, 0, 0);
}

// global->LDS DMA, 16B per lane; ldsp must be wave-uniform (lane i lands at
// ldsp + i*16).
__device__ __forceinline__ void gld16(const void* g, void* l) {
    __builtin_amdgcn_global_load_lds(
        (const __attribute__((address_space(1))) unsigned int*)g,
        (__attribute__((address_space(3))) unsigned int*)l, 16, 0, 0);
}

// ------- fused prep: pack x + transpose both weights + RoPE table --------
__global__ __launch_bounds__(256)
void prep(const float* __restrict__ x, const float* __restrict__ w_qkv,
          const float* __restrict__ w_out, ushort* __restrict__ xb,
          ushort* __restrict__ wqkvT, ushort* __restrict__ woutT,
          float2* __restrict__ rope_tbl)
{
    __shared__ ushort tile[64][66];
    const int blk = blockIdx.x, t = threadIdx.x;
    if (blk >= 1280) {                      // RoPE cos/sin table [2048][32]
        const int idx = (blk - 1280) * 256 + t;      // 0..4095
        const int n = idx >> 1, fbase = (idx & 1) * 16;
#pragma unroll
        for (int f = 0; f < 16; ++f) {
            const float inv = __expf(-(float)(fbase + f) * (9.2103403719761836f / 32.0f));
            float sn, cs;
            __sincosf((float)n * inv, &sn, &cs);
            rope_tbl[(size_t)n * 32 + fbase + f] = make_float2(cs, sn);
        }
        return;
    }
    if (blk < 1024) {                       // pack x -> bf16
        const int i = (blk * 256 + t) * 8;
        float4 a = *(const float4*)&x[i];
        float4 b = *(const float4*)&x[i + 4];
        union { ushort us[8]; uint4 v; } pk;
        pk.us[0] = f2bf(a.x); pk.us[1] = f2bf(a.y); pk.us[2] = f2bf(a.z); pk.us[3] = f2bf(a.w);
        pk.us[4] = f2bf(b.x); pk.us[5] = f2bf(b.y); pk.us[6] = f2bf(b.z); pk.us[7] = f2bf(b.w);
        *(uint4*)&xb[i] = pk.v;
        return;
    }
    const float* w; ushort* wT; int K, N, n0, k0;
    if (blk < 1216) { const int s = blk - 1024; w = w_qkv; wT = wqkvT; K = 512; N = 1536; n0 = (s % 24) * 64; k0 = (s / 24) * 64; }
    else            { const int s = blk - 1216; w = w_out; wT = woutT; K = 512; N = 512;  n0 = (s % 8) * 64;  k0 = (s / 8) * 64; }
#pragma unroll
    for (int i = 0; i < 4; ++i) {
        const int slot = t + i * 256;
        const int r = slot >> 4, c4 = (slot & 15) * 4;
        float4 v = *(const float4*)&w[(size_t)(k0 + r) * N + n0 + c4];
        tile[c4 + 0][r] = f2bf(v.x);
        tile[c4 + 1][r] = f2bf(v.y);
        tile[c4 + 2][r] = f2bf(v.z);
        tile[c4 + 3][r] = f2bf(v.w);
    }
    __syncthreads();
    const int n = t >> 2, kc = (t & 3) * 16;
    union { ushort us[16]; uint4 v[2]; } o;
#pragma unroll
    for (int j = 0; j < 16; ++j) o.us[j] = tile[n][kc + j];
    *(uint4*)&wT[(size_t)(n0 + n) * K + k0 + kc]     = o.v[0];
    *(uint4*)&wT[(size_t)(n0 + n) * K + k0 + kc + 8] = o.v[1];
}

// ---------- QKV GEMM 64x128, global_load_lds staging, + RoPE epilogue ----
// R4: sincos via precomputed table (512KB, L2-resident) -- the 32 __sincosf
// + 4 __expf per thread (~500 VALU ops) were comparable to the MFMA loop.
__global__ __launch_bounds__(256)
void gemm_qkv_rope(const ushort* __restrict__ xb, const ushort* __restrict__ wT,
                   ushort* __restrict__ qb, ushort* __restrict__ kb,
                   ushort* __restrict__ vtb, const float2* __restrict__ rope_tbl)
{
    __shared__ __align__(16) ushort As[64][64];    // unpadded: DMA target
    __shared__ __align__(16) ushort Bs[128][64];
    const int t = threadIdx.x, lane = t & 63, w = t >> 6;
    const int quad = lane >> 4, l16 = lane & 15;
    const int m0 = blockIdx.y * 64, n0 = blockIdx.x * 128;
    const int mw = (w >> 1) * 32, nw = (w & 1) * 64;
    const int krow = lane >> 3, kcol = (lane & 7) * 8;   // DMA lane mapping
    f32x4 acc[2][4] = {};

    for (int k0 = 0; k0 < 512; k0 += 64) {
        __syncthreads();   // previous tile's readers done
        gld16(&xb[(size_t)(m0 + w * 8 + krow) * 512 + k0 + kcol],        &As[w * 8][0]);
        gld16(&xb[(size_t)(m0 + (w + 4) * 8 + krow) * 512 + k0 + kcol],  &As[(w + 4) * 8][0]);
#pragma unroll
        for (int jj = 0; jj < 4; ++jj) {
            const int j = w * 4 + jj;
            gld16(&wT[(size_t)(n0 + j * 8 + krow) * 512 + k0 + kcol], &Bs[j * 8][0]);
        }
        __syncthreads();   // vmcnt drained -> tiles ready
#pragma unroll
        for (int ks = 0; ks < 2; ++ks) {
            short8 a[2], b[4];
#pragma unroll
            for (int i = 0; i < 2; ++i)
                a[i] = *(const short8*)&As[mw + i * 16 + l16][ks * 32 + quad * 8];
#pragma unroll
            for (int j = 0; j < 4; ++j)
                b[j] = *(const short8*)&Bs[nw + j * 16 + l16][ks * 32 + quad * 8];
#pragma unroll
            for (int i = 0; i < 2; ++i)
#pragma unroll
                for (int j = 0; j < 4; ++j)
                    acc[i][j] = mfma16(a[i], b[j], acc[i][j]);
        }
    }

    const int sec = (n0 + nw) >> 9;   // 0=q 1=k 2=v, wave-uniform
    if (sec == 2) {
#pragma unroll
        for (int i = 0; i < 2; ++i) {
            const int m = m0 + mw + i * 16 + quad * 4;
            const int bidx = m >> 11, n = m & 2047;
#pragma unroll
            for (int j = 0; j < 4; ++j) {
                const int nc = n0 + nw + j * 16 + l16;
                const int d = nc & 63, h = (nc >> 6) & 7;
                ushort4 pk;
                pk.x = f2bf(acc[i][j][0]); pk.y = f2bf(acc[i][j][1]);
                pk.z = f2bf(acc[i][j][2]); pk.w = f2bf(acc[i][j][3]);
                *(ushort4*)&vtb[(((size_t)bidx * 8 + h) * 64 + d) * 2048 + n] = pk;
            }
        }
    } else {
        ushort* dst = (sec == 0) ? qb : kb;
        const float scale = (sec == 0) ? 0.125f : 1.0f;
#pragma unroll
        for (int j = 0; j < 4; ++j) {
            const int nc = n0 + nw + j * 16 + l16;
            const int d = nc & 63, h = (nc >> 6) & 7;
            const float2* tb = rope_tbl + (d >> 1);
#pragma unroll
            for (int i = 0; i < 2; ++i)
#pragma unroll
            for (int r = 0; r < 4; ++r) {
                const int m = m0 + mw + i * 16 + quad * 4 + r;
                const int bidx = m >> 11, n = m & 2047;
                const float2 cs2 = tb[(size_t)n * 32];
                const float vacc = acc[i][j][r];
                const float partner = __shfl_xor(vacc, 1);
                const float rot = (d & 1) ? (vacc * cs2.x + partner * cs2.y)
                                          : (vacc * cs2.x - partner * cs2.y);
                dst[(((size_t)bidx * 8 + h) * 2048 + n) * 64 + d] = f2bf(rot * scale);
            }
        }
    }
}

// -------- flash attention R4: QBLK=128 on the R3 schedule ----------------
// Flash is bytes-bound: R3 hit the ~6.9 TB/s delivery ceiling (512 MB
// requested / 74 us floor, matches the fillBuffer stream rate). QBLK=128
// halves the K/V re-reads: 512 -> 384 MB. Schedule is exactly R3's
// (reg-bias issued 2 iters ahead, triple-buffered K/V via gld16, counted
// vmcnt, ONE barrier/iter) -- R2's QBLK=128 failure was its LDS-bias +
// barrier-coupled drain, not the tiling. Per-wave shapes unchanged; 8 waves.
// Per-iter per-wave VMEM: stage=2 gld16 (K:1, V:1), bias=16 -> steady wait
// vmcnt(34) = bias(it)16 + stage(it+1)2 + bias(it+1)16 (drains tile-it K/V
// only). Last iter: vmcnt(16). LDS 66KB.
__global__ __launch_bounds__(512)
void flash_attn_mfma(const ushort* __restrict__ qb, const ushort* __restrict__ kb,
                     const ushort* __restrict__ vtb, const float* __restrict__ bias,
                     ushort* __restrict__ ob)
{
    __shared__ __align__(16) ushort Ks[3][64][64];   // 24KB, swizzled, DMA tgt
    __shared__ __align__(16) ushort Vt[3][64][64];   // 24KB, [dim][seq], swz
    __shared__ __align__(16) ushort Ps[8][16][72];   // 18KB
    const int t = threadIdx.x, lane = t & 63, w = t >> 6;   // w in [0,8)
    const int quad = lane >> 4, l16 = lane & 15;
    const int q0 = blockIdx.x * 128, h = blockIdx.y, b = blockIdx.z;
    const size_t bh = (size_t)(b * NHEAD + h);
    const ushort* Q  = qb  + bh * SEQ * HDIM;
    const ushort* Kp = kb  + bh * SEQ * HDIM;
    const ushort* VT = vtb + bh * HDIM * SEQ;
    const float*  Bp = bias + ((size_t)h * SEQ + q0 + w * 16) * SEQ;  // wave's rows

    f32x4 oacc[4] = {};
    float lsum[4] = {};
    const int krow = lane >> 3;                       // K/V DMA row-in-8
    const int kcolsw = ((lane & 7) ^ krow) * 8;       // swizzled source chunk

    // swizzled read columns: logical chunk (ks*4+quad) at row with row&7==l16&7
    const int sw = l16 & 7;
    const int c0 = (quad ^ sw) * 8;           // ks=0
    const int c1 = ((quad + 4) ^ sw) * 8;     // ks=1

    short8 qf[2];
    qf[0] = *(const short8*)&Q[(size_t)(q0 + w * 16 + l16) * HDIM + quad * 8];
    qf[1] = *(const short8*)&Q[(size_t)(q0 + w * 16 + l16) * HDIM + 32 + quad * 8];
    asm volatile("" ::: "memory");   // Q loads issued before staging groups

    float b0[16], b1[16];

    // stage K/V tile IT_ into LDS buffer BUF (2 gld16 / thread, 8 waves:
    // wave w's single gld16 covers rows w*8..w*8+7 = the whole 64-row tile)
#define FA_STAGE(BUF, IT_)                                                          \
    {                                                                               \
        const int k2_ = (IT_) * 64;                                                 \
        gld16(&Kp[(size_t)(k2_ + w * 8 + krow) * HDIM + kcolsw], &Ks[BUF][w * 8][0]); \
        gld16(&VT[(size_t)(w * 8 + krow) * SEQ + k2_ + kcolsw],  &Vt[BUF][w * 8][0]); \
    }

    // bias tile IT_ -> 16 fp32 registers (row quad*4+r, col s*16+l16)
#define FA_BIAS(BREG, IT_)                                                          \
    {                                                                               \
        const int k2_ = (IT_) * 64;                                                 \
        _Pragma("unroll")                                                           \
        for (int r = 0; r < 4; ++r)                                                 \
            _Pragma("unroll")                                                       \
            for (int s = 0; s < 4; ++s)                                             \
                BREG[r * 4 + s] = Bp[(size_t)(quad * 4 + r) * SEQ + k2_ + s * 16 + l16]; \
    }

    // one iteration. WCNT: vmcnt immediate at top. REFILL: issue it+2 loads.
#define FA_BODY(IT, BCUR, REFILL, WCNT)                                             \
    {                                                                               \
        asm volatile("s_waitcnt vmcnt(" #WCNT ")" ::: "memory");                    \
        __builtin_amdgcn_s_barrier();                                               \
        const int cb_ = (IT) % 3;                                                   \
        if (REFILL) {                                                               \
            FA_STAGE(((IT) + 2) % 3, (IT) + 2);                                     \
            asm volatile("" ::: "memory");   /* pin: stage before bias */           \
        }                                                                           \
        f32x4 sacc[4] = {};                                                         \
        __builtin_amdgcn_s_setprio(1);                                              \
        _Pragma("unroll")                                                           \
        for (int s = 0; s < 4; ++s) {                                               \
            short8 kf0 = *(const short8*)&Ks[cb_][s * 16 + l16][c0];                \
            sacc[s] = mfma16(qf[0], kf0, sacc[s]);                                  \
            short8 kf1 = *(const short8*)&Ks[cb_][s * 16 + l16][c1];                \
            sacc[s] = mfma16(qf[1], kf1, sacc[s]);                                  \
        }                                                                           \
        __builtin_amdgcn_s_setprio(0);                                              \
        _Pragma("unroll")                                                           \
        for (int r = 0; r < 4; ++r)                                                 \
            _Pragma("unroll")                                                       \
            for (int s = 0; s < 4; ++s) {                                           \
                const float p = __expf(sacc[s][r] + BCUR[r * 4 + s]);               \
                lsum[r] += p;                                                       \
                Ps[w][quad * 4 + r][s * 16 + l16] = f2bf(p);                        \
            }                                                                       \
        if (REFILL) FA_BIAS(BCUR, (IT) + 2);                                        \
        asm volatile("" ::: "memory");   /* Ps writes before Ps reads */            \
        __builtin_amdgcn_s_setprio(1);                                              \
        _Pragma("unroll")                                                           \
        for (int ks = 0; ks < 2; ++ks) {                                            \
            short8 pf = *(const short8*)&Ps[w][l16][ks * 32 + quad * 8];            \
            const int cc_ = ks ? c1 : c0;                                           \
            _Pragma("unroll")                                                       \
            for (int s = 0; s < 4; ++s) {                                           \
                short8 vf = *(const short8*)&Vt[cb_][s * 16 + l16][cc_];            \
                oacc[s] = mfma16(pf, vf, oacc[s]);                                  \
            }                                                                       \
        }                                                                           \
        __builtin_amdgcn_s_setprio(0);                                              \
    }

    // prologue: group(0) then group(1), order pinned
    FA_STAGE(0, 0);
    asm volatile("" ::: "memory");
    FA_BIAS(b0, 0);
    asm volatile("" ::: "memory");
    FA_STAGE(1, 1);
    asm volatile("" ::: "memory");
    FA_BIAS(b1, 1);

    for (int i2 = 0; i2 < 15; ++i2) {
        FA_BODY(2 * i2,     b0, 1, 34);
        FA_BODY(2 * i2 + 1, b1, 1, 34);
    }
    FA_BODY(30, b0, 0, 34);
    FA_BODY(31, b1, 0, 16);

#undef FA_BODY
#undef FA_BIAS
#undef FA_STAGE

    // epilogue: cross-lane row-sum, normalize, write attnb [4096][512]
#pragma unroll
    for (int r = 0; r < 4; ++r) {
        float rs = lsum[r];
        rs += __shfl_xor(rs, 1, 16);
        rs += __shfl_xor(rs, 2, 16);
        rs += __shfl_xor(rs, 4, 16);
        rs += __shfl_xor(rs, 8, 16);
        const float invl = 1.0f / rs;
        const size_t m = (size_t)b * SEQ + q0 + w * 16 + quad * 4 + r;
#pragma unroll
        for (int s = 0; s < 4; ++s)
            ob[m * 512 + h * HDIM + s * 16 + l16] = f2bf(oacc[s][r] * invl);
    }
}

// ---------- out GEMM 64x64, global_load_lds staging ----------------------
__global__ __launch_bounds__(256)
void gemm_out(const ushort* __restrict__ Ab, const ushort* __restrict__ wT,
              float* __restrict__ C)
{
    __shared__ __align__(16) ushort As[64][64];
    __shared__ __align__(16) ushort Bs[64][64];
    const int t = threadIdx.x, lane = t & 63, w = t >> 6;
    const int quad = lane >> 4, l16 = lane & 15;
    const int m0 = blockIdx.y * 64, n0 = blockIdx.x * 64;
    const int mw = (w >> 1) * 32, nw = (w & 1) * 32;
    const int krow = lane >> 3, kcol = (lane & 7) * 8;
    f32x4 acc[2][2] = {};

    for (int k0 = 0; k0 < 512; k0 += 64) {
        __syncthreads();
        gld16(&Ab[(size_t)(m0 + w * 8 + krow) * 512 + k0 + kcol],       &As[w * 8][0]);
        gld16(&Ab[(size_t)(m0 + (w + 4) * 8 + krow) * 512 + k0 + kcol], &As[(w + 4) * 8][0]);
        gld16(&wT[(size_t)(n0 + w * 8 + krow) * 512 + k0 + kcol],       &Bs[w * 8][0]);
        gld16(&wT[(size_t)(n0 + (w + 4) * 8 + krow) * 512 + k0 + kcol], &Bs[(w + 4) * 8][0]);
        __syncthreads();
#pragma unroll
        for (int ks = 0; ks < 2; ++ks) {
            short8 a[2], b[2];
#pragma unroll
            for (int i = 0; i < 2; ++i)
                a[i] = *(const short8*)&As[mw + i * 16 + l16][ks * 32 + quad * 8];
#pragma unroll
            for (int j = 0; j < 2; ++j)
                b[j] = *(const short8*)&Bs[nw + j * 16 + l16][ks * 32 + quad * 8];
#pragma unroll
            for (int i = 0; i < 2; ++i)
#pragma unroll
                for (int j = 0; j < 2; ++j)
                    acc[i][j] = mfma16(a[i], b[j], acc[i][j]);
        }
    }
#pragma unroll
    for (int i = 0; i < 2; ++i)
#pragma unroll
    for (int r = 0; r < 4; ++r) {
        const int m = m0 + mw + i * 16 + quad * 4 + r;
#pragma unroll
        for (int j = 0; j < 2; ++j)
            C[(size_t)m * 512 + n0 + nw + j * 16 + l16] = acc[i][j][r];
    }
}

extern "C" void kernel_launch(void* const* d_in, const int* in_sizes, int n_in,
                              void* d_out, int out_size, void* d_ws, size_t ws_size,
                              hipStream_t stream)
{
    const float* x        = (const float*)d_in[0];
    const float* pos_bias = (const float*)d_in[1];
    const float* w_qkv    = (const float*)d_in[2];
    const float* w_out    = (const float*)d_in[3];
    float* out = (float*)d_out;

    char* ws = (char*)d_ws;
    ushort* xb     = (ushort*)(ws);                            // 4 MB
    ushort* wqkvT  = (ushort*)(ws + 4194304);                  // 1.5 MB
    ushort* woutT  = (ushort*)(ws + 5767168);                  // 0.5 MB
    ushort* qb     = (ushort*)(ws + 6291456);                  // 4 MB
    ushort* kb     = (ushort*)(ws + 10485760);                 // 4 MB
    ushort* vtb    = (ushort*)(ws + 14680064);                 // 4 MB (V^T)
    ushort* attnb  = (ushort*)(ws + 18874368);                 // 4 MB
    float2* ropetb = (float2*)(ws + 23068672);                 // 512 KB

    prep<<<1296, 256, 0, stream>>>(x, w_qkv, w_out, xb, wqkvT, woutT, ropetb);
    gemm_qkv_rope<<<dim3(12, 64), 256, 0, stream>>>(xb, wqkvT, qb, kb, vtb, ropetb);
    flash_attn_mfma<<<dim3(SEQ / 128, NHEAD, BATCH), 512, 0, stream>>>(qb, kb, vtb, pos_bias, attnb);
    gemm_out<<<dim3(8, 64), 256, 0, stream>>>(attnb, woutT, out);
}